// Round 9
// baseline (2185.056 us; speedup 1.0000x reference)
//
#include <hip/hip_runtime.h>
#include <cstdint>
#include <cstddef>

#define B_   256
#define T_   512
#define E_   128
#define H_   256

typedef _Float16 f16x8 __attribute__((ext_vector_type(8)));
typedef _Float16 f16x4 __attribute__((ext_vector_type(4)));
typedef float    f32x4 __attribute__((ext_vector_type(4)));

__device__ __forceinline__ float sigm(float x) { return 1.f / (1.f + __expf(-x)); }
__device__ __forceinline__ float tanh_(float x) {
  x = fminf(15.f, fmaxf(-15.f, x));
  float e = __expf(2.f * x);
  return (e - 1.f) / (e + 1.f);
}
__device__ __forceinline__ void poll_ge(const int* p, int v) {
  while (__hip_atomic_load(p, __ATOMIC_ACQUIRE, __HIP_MEMORY_SCOPE_AGENT) < v)
    __builtin_amdgcn_s_sleep(4);
}
__device__ __forceinline__ void pin(f16x8& x) { asm volatile("" : "+v"(x)); }

// ---------------- prep: swizzle weights to MFMA fragment order (fp16) -----------------------
// WSW[dir][kc(12)][tile(48)][lane(64)][8] fp16. kc 0..7: W_hh (K=256), kc 8..11: W_ih (K=128).
// Fragment: lane l supplies W[tile*16+(l&15)][k=(l>>4)*8+j]. Tiles 0..15=r, 16..31=z, 32..47=n.
__global__ __launch_bounds__(256) void prep_kernel(
    const float* __restrict__ whhf, const float* __restrict__ whhb,
    const float* __restrict__ wihf, const float* __restrict__ wihb,
    _Float16* __restrict__ WSW)
{
  int idx = blockIdx.x * 256 + threadIdx.x;   // 288 blocks -> 73728 exactly
  int lane = idx & 63;
  int tile = (idx >> 6) % 48;
  int kc   = (idx / 3072) % 12;
  int dir  = idx / 36864;
  int ncol = tile * 16 + (lane & 15);
  int quad = lane >> 4;
  const float* src;
  if (kc < 8) {
    const float* w = dir ? whhb : whhf;       // [768][256] row-major
    src = w + (size_t)ncol * H_ + kc * 32 + quad * 8;
  } else {
    const float* w = dir ? wihb : wihf;       // [768][128] row-major
    src = w + (size_t)ncol * E_ + (kc - 8) * 32 + quad * 8;
  }
  f16x8 v;
  #pragma unroll
  for (int j = 0; j < 8; ++j) v[j] = (_Float16)src[j];
  *(f16x8*)(WSW + (size_t)idx * 8) = v;
}

// ------- rank rows by length (desc) + init flags --------------------------------------------
__global__ void sort_kernel(const int* __restrict__ lens, int* __restrict__ order,
                            int* __restrict__ flags)
{
  int i = threadIdx.x;                        // one block of 256
  for (int k = i; k < 1024; k += 256) flags[k] = 0;
  for (int k = i; k < 512;  k += 256) flags[1024 + k] = -1;
  int li = lens[i];
  int rank = 0;
  for (int k = 0; k < B_; ++k) {
    int lk = lens[k];
    rank += (lk > li) || (lk == li && k < i);
  }
  order[rank] = i;
}

// ---------------- fused scan + xp producers, 96 blocks x 256 thr -----------------------------
// R8 finding: 512-thr blocks (2 waves/SIMD) cap regs at 256/wave -> only 4 weight sets fit
// (128 AGPR + 124 arch = full), rest streamed from LDS (196 KB/CU/step). Fix: 256-thr blocks,
// 1 wave/SIMD, 512-reg budget. Consumer wave owns 64 units = 12 tile-sets: 10 in regs (320),
// 2 (n-gate j=2,3) in LDS. Per-step LDS: 8 hf (rolling) + 16 wl reads/wave -> ~80 KB/CU.
// Producers: 2 per group, 4 waves, 12 tiles/wave, chunk protocol unchanged.
#define XPSLAB 196608        // halfs per (buf,g): 16 s x 12288
__global__ __launch_bounds__(256, 1) void fused_kernel(
    const _Float16* __restrict__ WSW, const int* __restrict__ seqs,
    const float* __restrict__ embed,
    const float* __restrict__ bihf, const float* __restrict__ bhhf,
    const float* __restrict__ bihb, const float* __restrict__ bhhb,
    const int* __restrict__ lens, const int* __restrict__ order,
    _Float16* __restrict__ XP, int* __restrict__ FLAGS, float* __restrict__ hcat)
{
  // union'd LDS arena:
  // consumer: [0,65536) wl: n-gate j=2,3 frags [w][jj][kc][lane][8]; [65536,82432) hbuf
  // producer: [0,17408) xstage[4][16][136]
  __shared__ __align__(16) char smem[82432];
  __shared__ int s_row[16], s_len[16];

  const int bid = blockIdx.x, tid = threadIdx.x;
  const int w = tid >> 6, lane = tid & 63, lm = lane & 15, lq = lane >> 4;

  if (bid < 32) {
    // ================= CONSUMER =================
    const int g = bid, dir = g & 1, grp = g >> 1;
    _Float16* wl = (_Float16*)smem;
    _Float16* hb = (_Float16*)(smem + 65536);              // [buf][chain16][264]
    if (tid < 16) { int r = order[grp * 16 + tid]; s_row[tid] = r; s_len[tid] = lens[r]; }
    for (int i = tid; i < 2 * 16 * 264; i += 256) hb[i] = (_Float16)0.f;

    const _Float16* wsd = WSW + (size_t)dir * 294912 + (size_t)lane * 8;
    // LDS sets: n-gate j=2,3 (tiles 34+4w, 35+4w)
    #pragma unroll
    for (int kc = 0; kc < 8; ++kc) {
      *(f16x8*)(wl + (((w * 2 + 0) * 8 + kc) * 64 + lane) * 8) =
          *(const f16x8*)(wsd + (size_t)kc * 24576 + (34 + 4 * w) * 512);
      *(f16x8*)(wl + (((w * 2 + 1) * 8 + kc) * 64 + lane) * 8) =
          *(const f16x8*)(wsd + (size_t)kc * 24576 + (35 + 4 * w) * 512);
    }
    // register sets: r j=0..3 (tiles 4w+j), z j=0..3 (16+4w+j), n j=0,1 (32+4w+j) = 320 VGPRs
    f16x8 wreg[10][8];
    #pragma unroll
    for (int s = 0; s < 10; ++s) {
      const int gate = s >> 2, j = s & 3;                  // s=8,9 -> gate=2, j=0,1
      const int tile = gate * 16 + 4 * w + j;
      #pragma unroll
      for (int kc = 0; kc < 8; ++kc) {
        wreg[s][kc] = *(const f16x8*)(wsd + (size_t)kc * 24576 + tile * 512);
        pin(wreg[s][kc]);
      }
    }
    const float* bhh = dir ? bhhb : bhhf;
    float bhn[4][4];
    #pragma unroll
    for (int j = 0; j < 4; ++j) {
      float4 b = *(const float4*)(bhh + 512 + 64 * w + 16 * j + lq * 4);
      bhn[j][0] = b.x; bhn[j][1] = b.y; bhn[j][2] = b.z; bhn[j][3] = b.w;
    }
    __syncthreads();
    const int len_l = s_len[lm], rowb = s_row[lm];
    int ml = 1;
    #pragma unroll
    for (int i = 0; i < 16; ++i) ml = max(ml, s_len[i]);

    int* doneP  = FLAGS + 1024 + g * 16;
    const int* readyA = FLAGS + g * 32;
    const int* readyB = FLAGS + g * 32 + 16;
    float h32r[4][4] = {};

    for (int t = 0; t < ml; ++t) {
      if ((t & 15) == 0) {                     // chunk boundary
        if (tid == 0) {
          if (t) __hip_atomic_store(doneP, (t >> 4) - 1,
                                    __ATOMIC_RELEASE, __HIP_MEMORY_SCOPE_AGENT);
          poll_ge(readyA, (t >> 4) + 1);
          poll_ge(readyB, (t >> 4) + 1);
        }
        __syncthreads();
      }
      // xp loads for THIS step (issued now, consumed at epilogue -> latency hidden)
      const _Float16* sb = XP + (size_t)((((t >> 4) & 1) * 32 + g)) * XPSLAB
                           + (size_t)(t & 15) * 12288 + lq * 64 + lm * 4;
      f16x4 xr[4], xz[4], xn[4];
      #pragma unroll
      for (int j = 0; j < 4; ++j) {
        xr[j] = *(const f16x4*)(sb + (4 * w + j)      * 256);
        xz[j] = *(const f16x4*)(sb + (16 + 4 * w + j) * 256);
        xn[j] = *(const f16x4*)(sb + (32 + 4 * w + j) * 256);
      }

      f32x4 ar[4] = {}, az[4] = {}, an[4] = {};
      const _Float16* hrow = hb + ((size_t)(t & 1) * 16 + lm) * 264 + lq * 8;
      f16x8 hcur = *(const f16x8*)(hrow);
      #pragma unroll
      for (int kc = 0; kc < 8; ++kc) {
        f16x8 hnext = (kc < 7) ? *(const f16x8*)(hrow + (kc + 1) * 32) : hcur;
        f16x8 wl0 = *(const f16x8*)(wl + (((w * 2 + 0) * 8 + kc) * 64 + lane) * 8);
        f16x8 wl1 = *(const f16x8*)(wl + (((w * 2 + 1) * 8 + kc) * 64 + lane) * 8);
        ar[0] = __builtin_amdgcn_mfma_f32_16x16x32_f16(wreg[0][kc], hcur, ar[0], 0, 0, 0);
        ar[1] = __builtin_amdgcn_mfma_f32_16x16x32_f16(wreg[1][kc], hcur, ar[1], 0, 0, 0);
        ar[2] = __builtin_amdgcn_mfma_f32_16x16x32_f16(wreg[2][kc], hcur, ar[2], 0, 0, 0);
        ar[3] = __builtin_amdgcn_mfma_f32_16x16x32_f16(wreg[3][kc], hcur, ar[3], 0, 0, 0);
        az[0] = __builtin_amdgcn_mfma_f32_16x16x32_f16(wreg[4][kc], hcur, az[0], 0, 0, 0);
        az[1] = __builtin_amdgcn_mfma_f32_16x16x32_f16(wreg[5][kc], hcur, az[1], 0, 0, 0);
        az[2] = __builtin_amdgcn_mfma_f32_16x16x32_f16(wreg[6][kc], hcur, az[2], 0, 0, 0);
        az[3] = __builtin_amdgcn_mfma_f32_16x16x32_f16(wreg[7][kc], hcur, az[3], 0, 0, 0);
        an[0] = __builtin_amdgcn_mfma_f32_16x16x32_f16(wreg[8][kc], hcur, an[0], 0, 0, 0);
        an[1] = __builtin_amdgcn_mfma_f32_16x16x32_f16(wreg[9][kc], hcur, an[1], 0, 0, 0);
        an[2] = __builtin_amdgcn_mfma_f32_16x16x32_f16(wl0,        hcur, an[2], 0, 0, 0);
        an[3] = __builtin_amdgcn_mfma_f32_16x16x32_f16(wl1,        hcur, an[3], 0, 0, 0);
        hcur = hnext;
      }
      // epilogue: lane = (chain lm, units 64w + 16j + lq*4 + i)
      #pragma unroll
      for (int j = 0; j < 4; ++j) {
        union { f16x4 h4; unsigned long long q; } pk;
        #pragma unroll
        for (int i = 0; i < 4; ++i) {
          float r = sigm((float)xr[j][i] + ar[j][i]);
          float z = sigm((float)xz[j][i] + az[j][i]);
          float n = tanh_((float)xn[j][i] + r * (an[j][i] + bhn[j][i]));
          float hn = (t < len_l) ? ((1.f - z) * n + z * h32r[j][i]) : h32r[j][i];
          h32r[j][i] = hn;
          pk.h4[i] = (_Float16)hn;
        }
        *(f16x4*)(hb + ((size_t)((t + 1) & 1) * 16 + lm) * 264 + 64 * w + 16 * j + lq * 4) = pk.h4;
      }
      __syncthreads();                         // h(t+1) visible; one barrier per step
    }
    if (tid == 0)
      __hip_atomic_store(doneP, 999, __ATOMIC_RELEASE, __HIP_MEMORY_SCOPE_AGENT);
    #pragma unroll
    for (int j = 0; j < 4; ++j) {
      float4 o; o.x = h32r[j][0]; o.y = h32r[j][1]; o.z = h32r[j][2]; o.w = h32r[j][3];
      *(float4*)(&hcat[(size_t)rowb * (2 * H_) + dir * H_ + 64 * w + 16 * j + lq * 4]) = o;
    }
  } else {
    // ================= PRODUCER =================
    const int pb = bid - 32, g = pb >> 1, half = pb & 1;
    const int dir = g & 1, grp = g >> 1;
    _Float16* xs = (_Float16*)smem;                        // [sb4][chain16][136]
    if (tid < 16) { int r = order[grp * 16 + tid]; s_row[tid] = r; s_len[tid] = lens[r]; }
    __syncthreads();
    int ml = 1;
    #pragma unroll
    for (int i = 0; i < 16; ++i) ml = max(ml, s_len[i]);
    const int nch = (ml + 15) >> 4;

    const int chain = tid >> 4, q = tid & 15;  // x-staging: 16 threads/chain, 8 floats each
    const int rowb = s_row[chain], lenr = s_len[chain];
    const _Float16* wsd = WSW + (size_t)dir * 294912 + (size_t)lane * 8;
    const float* bih = dir ? bihb : bihf;
    const float* bhh = dir ? bhhb : bhhf;
    const int* doneP = FLAGS + 1024 + g * 16;
    int* readyP = FLAGS + g * 32 + half * 16;

    // wave w owns tiles w, w+4, ..., w+44 (12): weights (192 regs) + biases pinned/hoisted
    f16x8 wA[12][4];
    float bb[12][4];
    #pragma unroll
    for (int ti = 0; ti < 12; ++ti) {
      const int tile = w + 4 * ti;
      #pragma unroll
      for (int kc = 0; kc < 4; ++kc) {
        wA[ti][kc] = *(const f16x8*)(wsd + (size_t)(8 + kc) * 24576 + tile * 512);
        pin(wA[ti][kc]);
      }
      float4 bias = *(const float4*)(bih + tile * 16 + lq * 4);
      if (tile < 32) {                         // fold b_hh into r,z xp (n stays separate)
        float4 b2 = *(const float4*)(bhh + tile * 16 + lq * 4);
        bias.x += b2.x; bias.y += b2.y; bias.z += b2.z; bias.w += b2.w;
      }
      bb[ti][0] = bias.x; bb[ti][1] = bias.y; bb[ti][2] = bias.z; bb[ti][3] = bias.w;
    }

    for (int c = 0; c < nch; ++c) {
      if (c >= 2) { if (tid == 0) poll_ge(doneP, c - 2); __syncthreads(); }
      _Float16* slab = XP + (size_t)((c & 1) * 32 + g) * XPSLAB;
      #pragma unroll
      for (int batch = 0; batch < 2; ++batch) {
        #pragma unroll
        for (int sb = 0; sb < 4; ++sb) {       // stage x for 4 s-values
          int s = c * 16 + half * 8 + batch * 4 + sb;
          int p = dir ? (lenr - 1 - s) : s;
          p = min(max(p, 0), T_ - 1);
          int tok = seqs[(size_t)rowb * T_ + p];
          const float* er = embed + (size_t)tok * E_ + q * 8;
          float4 f0 = *(const float4*)(er);
          float4 f1 = *(const float4*)(er + 4);
          f16x4 h0; h0[0] = (_Float16)f0.x; h0[1] = (_Float16)f0.y;
          h0[2] = (_Float16)f0.z; h0[3] = (_Float16)f0.w;
          f16x4 h1; h1[0] = (_Float16)f1.x; h1[1] = (_Float16)f1.y;
          h1[2] = (_Float16)f1.z; h1[3] = (_Float16)f1.w;
          *(f16x4*)(xs + ((size_t)sb * 16 + chain) * 136 + q * 8)     = h0;
          *(f16x4*)(xs + ((size_t)sb * 16 + chain) * 136 + q * 8 + 4) = h1;
        }
        __syncthreads();
        f16x8 bx[4][4];
        #pragma unroll
        for (int sb = 0; sb < 4; ++sb)
          #pragma unroll
          for (int kc = 0; kc < 4; ++kc)
            bx[sb][kc] = *(const f16x8*)(xs + ((size_t)sb * 16 + lm) * 136 + kc * 32 + lq * 8);
        #pragma unroll
        for (int ti = 0; ti < 12; ++ti) {
          const int tile = w + 4 * ti;
          f32x4 acc[4] = {};
          #pragma unroll
          for (int kc = 0; kc < 4; ++kc) {
            acc[0] = __builtin_amdgcn_mfma_f32_16x16x32_f16(wA[ti][kc], bx[0][kc], acc[0], 0, 0, 0);
            acc[1] = __builtin_amdgcn_mfma_f32_16x16x32_f16(wA[ti][kc], bx[1][kc], acc[1], 0, 0, 0);
            acc[2] = __builtin_amdgcn_mfma_f32_16x16x32_f16(wA[ti][kc], bx[2][kc], acc[2], 0, 0, 0);
            acc[3] = __builtin_amdgcn_mfma_f32_16x16x32_f16(wA[ti][kc], bx[3][kc], acc[3], 0, 0, 0);
          }
          #pragma unroll
          for (int sb = 0; sb < 4; ++sb) {
            int s_local = half * 8 + batch * 4 + sb;
            f16x4 o;
            #pragma unroll
            for (int i = 0; i < 4; ++i) o[i] = (_Float16)(acc[sb][i] + bb[ti][i]);
            *(f16x4*)(slab + (size_t)s_local * 12288 + tile * 256 + lq * 64 + lm * 4) = o;
          }
        }
        __syncthreads();                       // drains; xstage reusable
      }
      if (tid == 0)
        __hip_atomic_store(readyP, c + 1, __ATOMIC_RELEASE, __HIP_MEMORY_SCOPE_AGENT);
    }
  }
}

// ---------------- final FC: out[b][c] = hcat[b] . W_fc[c] + b_fc[c] ----------------
__global__ __launch_bounds__(512) void fc_kernel(
    const float* __restrict__ hcat, const float* __restrict__ wfc,
    const float* __restrict__ bfc, float* __restrict__ out)
{
  const int b = blockIdx.x, t = threadIdx.x;
  float h  = hcat[(size_t)b * 512 + t];
  float p0 = h * wfc[t];
  float p1 = h * wfc[512 + t];
  #pragma unroll
  for (int off = 32; off > 0; off >>= 1) {
    p0 += __shfl_down(p0, off);
    p1 += __shfl_down(p1, off);
  }
  __shared__ float s0[8], s1[8];
  if ((t & 63) == 0) { s0[t >> 6] = p0; s1[t >> 6] = p1; }
  __syncthreads();
  if (t == 0) {
    float a = bfc[0], c = bfc[1];
    #pragma unroll
    for (int i = 0; i < 8; ++i) { a += s0[i]; c += s1[i]; }
    out[b * 2 + 0] = a;
    out[b * 2 + 1] = c;
  }
}

extern "C" void kernel_launch(void* const* d_in, const int* in_sizes, int n_in,
                              void* d_out, int out_size, void* d_ws, size_t ws_size,
                              hipStream_t stream)
{
  (void)in_sizes; (void)n_in; (void)out_size; (void)ws_size;
  const int*   seqs  = (const int*)d_in[0];
  const int*   lens  = (const int*)d_in[1];
  const float* embed = (const float*)d_in[2];
  const float* wihf  = (const float*)d_in[3];
  const float* whhf  = (const float*)d_in[4];
  const float* bihf  = (const float*)d_in[5];
  const float* bhhf  = (const float*)d_in[6];
  const float* wihb  = (const float*)d_in[7];
  const float* whhb  = (const float*)d_in[8];
  const float* bihb  = (const float*)d_in[9];
  const float* bhhb  = (const float*)d_in[10];
  const float* wfc   = (const float*)d_in[11];
  const float* bfc   = (const float*)d_in[12];
  float* out = (float*)d_out;

  // workspace layout (~25.6 MB)
  char* ws = (char*)d_ws;
  _Float16* WSW = (_Float16*)ws;                          // 1,179,648 B
  size_t off = 1179648;
  _Float16* XP  = (_Float16*)(ws + off); off += (size_t)2 * 32 * XPSLAB * 2;  // 25,165,824 B
  float* HCAT   = (float*)(ws + off);    off += (size_t)B_ * 2 * H_ * 4;      // 524,288 B
  int* ORDER    = (int*)(ws + off);      off += 1024;
  int* FLAGS    = (int*)(ws + off);      off += 6144;     // ready[1024] + done[512]

  prep_kernel<<<288, 256, 0, stream>>>(whhf, whhb, wihf, wihb, WSW);
  sort_kernel<<<1, 256, 0, stream>>>(lens, ORDER, FLAGS);
  fused_kernel<<<96, 256, 0, stream>>>(WSW, seqs, embed, bihf, bhhf, bihb, bhhb,
                                       lens, ORDER, XP, FLAGS, HCAT);
  fc_kernel<<<B_, 512, 0, stream>>>(HCAT, wfc, bfc, out);
}

// Round 10
// 1529.786 us; speedup vs baseline: 1.4283x; 1.4283x over previous
//
#include <hip/hip_runtime.h>
#include <cstdint>
#include <cstddef>

#define B_   256
#define T_   512
#define E_   128
#define H_   256

typedef _Float16 f16x8 __attribute__((ext_vector_type(8)));
typedef _Float16 f16x4 __attribute__((ext_vector_type(4)));
typedef float    f32x4 __attribute__((ext_vector_type(4)));

__device__ __forceinline__ float sigm(float x) { return 1.f / (1.f + __expf(-x)); }
__device__ __forceinline__ float tanh_(float x) {
  x = fminf(15.f, fmaxf(-15.f, x));
  float e = __expf(2.f * x);
  return (e - 1.f) / (e + 1.f);
}
__device__ __forceinline__ void poll_ge(const int* p, int v) {
  while (__hip_atomic_load(p, __ATOMIC_ACQUIRE, __HIP_MEMORY_SCOPE_AGENT) < v)
    __builtin_amdgcn_s_sleep(4);
}

// ---------------- prep: swizzle weights to MFMA fragment order (fp16) -----------------------
// WSW[dir][kc(12)][tile(48)][lane(64)][8] fp16. kc 0..7: W_hh (K=256), kc 8..11: W_ih (K=128).
// Fragment: lane l supplies W[tile*16+(l&15)][k=(l>>4)*8+j]. Tiles 0..15=r, 16..31=z, 32..47=n.
__global__ __launch_bounds__(256) void prep_kernel(
    const float* __restrict__ whhf, const float* __restrict__ whhb,
    const float* __restrict__ wihf, const float* __restrict__ wihb,
    _Float16* __restrict__ WSW)
{
  int idx = blockIdx.x * 256 + threadIdx.x;   // 288 blocks -> 73728 exactly
  int lane = idx & 63;
  int tile = (idx >> 6) % 48;
  int kc   = (idx / 3072) % 12;
  int dir  = idx / 36864;
  int ncol = tile * 16 + (lane & 15);
  int quad = lane >> 4;
  const float* src;
  if (kc < 8) {
    const float* w = dir ? whhb : whhf;       // [768][256] row-major
    src = w + (size_t)ncol * H_ + kc * 32 + quad * 8;
  } else {
    const float* w = dir ? wihb : wihf;       // [768][128] row-major
    src = w + (size_t)ncol * E_ + (kc - 8) * 32 + quad * 8;
  }
  f16x8 v;
  #pragma unroll
  for (int j = 0; j < 8; ++j) v[j] = (_Float16)src[j];
  *(f16x8*)(WSW + (size_t)idx * 8) = v;
}

// ------- rank rows by length (desc) + init flags --------------------------------------------
__global__ void sort_kernel(const int* __restrict__ lens, int* __restrict__ order,
                            int* __restrict__ flags)
{
  int i = threadIdx.x;                        // one block of 256
  for (int k = i; k < 1024; k += 256) flags[k] = 0;
  for (int k = i; k < 512;  k += 256) flags[1024 + k] = -1;
  int li = lens[i];
  int rank = 0;
  for (int k = 0; k < B_; ++k) {
    int lk = lens[k];
    rank += (lk > li) || (lk == li && k < i);
  }
  order[rank] = i;
}

// ---------------- fused scan + xp producers, 96 blocks ---------------------------------------
// R10 changes vs R7 (1431 us base):
//  (1) xp loaded at STEP TOP for the CURRENT step (consumed at epilogue ~2000 cyc later) —
//      R7 prefetched t+1 mid-step, so the per-step __syncthreads' vmcnt(0) drain ate the full
//      load latency every step (m97-style barrier drain).
//  (2) XCD-local mapping: consumer g's producers are blocks g+32 (half 0) and g+64 (half 1);
//      g+32 == g+64 == g (mod 8) -> same XCD under %8 round-robin -> xp reads hit LOCAL L2
//      (R7's 32+2g mapping made them cross-XCD LLC reads).
// Consumer: 512 thr, wave owns 32 units = 6 tile-sets: r,z (4) in regs, n (2) in LDS.
// Producer: 512 thr, 6 tiles/wave, weights+biases hoisted; chunk handoff every 16 steps.
#define XPSLAB 196608        // halfs per (buf,g): 16 s x 12288
__global__ __launch_bounds__(512, 1) void fused_kernel(
    const _Float16* __restrict__ WSW, const int* __restrict__ seqs,
    const float* __restrict__ embed,
    const float* __restrict__ bihf, const float* __restrict__ bhhf,
    const float* __restrict__ bihb, const float* __restrict__ bhhb,
    const int* __restrict__ lens, const int* __restrict__ order,
    _Float16* __restrict__ XP, int* __restrict__ FLAGS, float* __restrict__ hcat)
{
  // union'd LDS arena:
  // consumer: [0,131072) n-gate weight frags [w][set2][kc8][lane64][8]; [131072,148000) hbuf
  // producer: [0,17408) xstage[4][16][136]
  __shared__ __align__(16) char smem[147968];
  __shared__ int s_row[16], s_len[16];

  const int bid = blockIdx.x, tid = threadIdx.x;
  const int w = tid >> 6, lane = tid & 63, lm = lane & 15, lq = lane >> 4;

  if (bid < 32) {
    // ================= CONSUMER =================
    const int g = bid, dir = g & 1, grp = g >> 1;
    _Float16* wl = (_Float16*)smem;                        // n-gate frags
    _Float16* hb = (_Float16*)(smem + 131072);             // [buf][chain][264]
    if (tid < 16) { int r = order[grp * 16 + tid]; s_row[tid] = r; s_len[tid] = lens[r]; }
    for (int i = tid; i < 2 * 16 * 264; i += 512) hb[i] = (_Float16)0.f;

    const _Float16* wsd = WSW + (size_t)dir * 294912 + (size_t)lane * 8;
    #pragma unroll
    for (int kc = 0; kc < 8; ++kc) {                       // n tiles -> LDS (own-wave region)
      *(f16x8*)(wl + ((w * 2 + 0) * 8 + kc) * 512 + lane * 8) =
          *(const f16x8*)(wsd + (size_t)kc * 24576 + (32 + 2 * w) * 512);
      *(f16x8*)(wl + ((w * 2 + 1) * 8 + kc) * 512 + lane * 8) =
          *(const f16x8*)(wsd + (size_t)kc * 24576 + (33 + 2 * w) * 512);
    }
    f16x8 wh[4][8];                                        // r,z tiles -> regs (128)
    #pragma unroll
    for (int kc = 0; kc < 8; ++kc) {
      wh[0][kc] = *(const f16x8*)(wsd + (size_t)kc * 24576 + (2 * w)      * 512);
      wh[1][kc] = *(const f16x8*)(wsd + (size_t)kc * 24576 + (2 * w + 1)  * 512);
      wh[2][kc] = *(const f16x8*)(wsd + (size_t)kc * 24576 + (16 + 2 * w) * 512);
      wh[3][kc] = *(const f16x8*)(wsd + (size_t)kc * 24576 + (17 + 2 * w) * 512);
    }
    const float* bhh = dir ? bhhb : bhhf;
    float bhn[2][4];
    #pragma unroll
    for (int th = 0; th < 2; ++th) {
      float4 b = *(const float4*)(bhh + 512 + 32 * w + th * 16 + lq * 4);
      bhn[th][0] = b.x; bhn[th][1] = b.y; bhn[th][2] = b.z; bhn[th][3] = b.w;
    }
    __syncthreads();
    const int len_l = s_len[lm], rowb = s_row[lm];
    int ml = 1;
    #pragma unroll
    for (int i = 0; i < 16; ++i) ml = max(ml, s_len[i]);

    int* doneP  = FLAGS + 1024 + g * 16;
    const int* readyA = FLAGS + g * 32;
    const int* readyB = FLAGS + g * 32 + 16;
    float h32r[2][4] = {};

    for (int t = 0; t < ml; ++t) {
      if ((t & 15) == 0) {                     // chunk boundary
        if (tid == 0) {
          if (t) __hip_atomic_store(doneP, (t >> 4) - 1,
                                    __ATOMIC_RELEASE, __HIP_MEMORY_SCOPE_AGENT);
          poll_ge(readyA, (t >> 4) + 1);
          poll_ge(readyB, (t >> 4) + 1);
        }
        __syncthreads();
      }
      // xp for THIS step: issued now, consumed at epilogue (hidden under MFMA+LDS below);
      // loads complete before the epilogue, so the end-of-step barrier has nothing to drain.
      const _Float16* sb = XP + (size_t)(((t >> 4) & 1) * 32 + g) * XPSLAB
                           + (size_t)(t & 15) * 12288 + lq * 64 + lm * 4;
      f16x4 xpc[6];
      xpc[0] = *(const f16x4*)(sb + (2 * w)      * 256);
      xpc[1] = *(const f16x4*)(sb + (2 * w + 1)  * 256);
      xpc[2] = *(const f16x4*)(sb + (16 + 2 * w) * 256);
      xpc[3] = *(const f16x4*)(sb + (17 + 2 * w) * 256);
      xpc[4] = *(const f16x4*)(sb + (32 + 2 * w) * 256);
      xpc[5] = *(const f16x4*)(sb + (33 + 2 * w) * 256);

      f32x4 acc[6] = {};
      const _Float16* hrow = hb + ((size_t)(t & 1) * 16 + lm) * 264 + lq * 8;
      #pragma unroll
      for (int kc = 0; kc < 8; ++kc) {
        f16x8 hf = *(const f16x8*)(hrow + kc * 32);
        acc[0] = __builtin_amdgcn_mfma_f32_16x16x32_f16(wh[0][kc], hf, acc[0], 0, 0, 0);
        acc[1] = __builtin_amdgcn_mfma_f32_16x16x32_f16(wh[1][kc], hf, acc[1], 0, 0, 0);
        acc[2] = __builtin_amdgcn_mfma_f32_16x16x32_f16(wh[2][kc], hf, acc[2], 0, 0, 0);
        acc[3] = __builtin_amdgcn_mfma_f32_16x16x32_f16(wh[3][kc], hf, acc[3], 0, 0, 0);
        f16x8 w4 = *(const f16x8*)(wl + ((w * 2 + 0) * 8 + kc) * 512 + lane * 8);
        acc[4] = __builtin_amdgcn_mfma_f32_16x16x32_f16(w4, hf, acc[4], 0, 0, 0);
        f16x8 w5 = *(const f16x8*)(wl + ((w * 2 + 1) * 8 + kc) * 512 + lane * 8);
        acc[5] = __builtin_amdgcn_mfma_f32_16x16x32_f16(w5, hf, acc[5], 0, 0, 0);
      }
      // epilogue: lane = (chain lm, units 32w + th*16 + lq*4 + i). r,z biases folded into xp.
      #pragma unroll
      for (int th = 0; th < 2; ++th) {
        union { f16x4 h4; unsigned long long q; } pk;
        #pragma unroll
        for (int i = 0; i < 4; ++i) {
          float r = sigm((float)xpc[th][i]     + acc[th][i]);
          float z = sigm((float)xpc[2 + th][i] + acc[2 + th][i]);
          float n = tanh_((float)xpc[4 + th][i] + r * (acc[4 + th][i] + bhn[th][i]));
          float hn = (t < len_l) ? ((1.f - z) * n + z * h32r[th][i]) : h32r[th][i];
          h32r[th][i] = hn;
          pk.h4[i] = (_Float16)hn;
        }
        *(f16x4*)(hb + ((size_t)((t + 1) & 1) * 16 + lm) * 264 + 32 * w + th * 16 + lq * 4) = pk.h4;
      }
      __syncthreads();                         // h(t+1) visible; one barrier per step
    }
    if (tid == 0)
      __hip_atomic_store(doneP, 999, __ATOMIC_RELEASE, __HIP_MEMORY_SCOPE_AGENT);
    #pragma unroll
    for (int th = 0; th < 2; ++th) {
      float4 o; o.x = h32r[th][0]; o.y = h32r[th][1]; o.z = h32r[th][2]; o.w = h32r[th][3];
      *(float4*)(&hcat[(size_t)rowb * (2 * H_) + dir * H_ + 32 * w + th * 16 + lq * 4]) = o;
    }
  } else {
    // ================= PRODUCER =================
    // XCD-local mapping: block g+32 -> (g, half 0); block g+64 -> (g, half 1).
    const int pb = bid - 32, g = pb & 31, half = pb >> 5;
    const int dir = g & 1, grp = g >> 1;
    _Float16* xs = (_Float16*)smem;                        // [sb4][chain16][136]
    if (tid < 16) { int r = order[grp * 16 + tid]; s_row[tid] = r; s_len[tid] = lens[r]; }
    __syncthreads();
    int ml = 1;
    #pragma unroll
    for (int i = 0; i < 16; ++i) ml = max(ml, s_len[i]);
    const int nch = (ml + 15) >> 4;

    const int chain = tid >> 5, q = tid & 31;  // x-staging: 32 threads/chain
    const int rowb = s_row[chain], lenr = s_len[chain];
    const _Float16* wsd = WSW + (size_t)dir * 294912 + (size_t)lane * 8;
    const float* bih = dir ? bihb : bihf;
    const float* bhh = dir ? bhhb : bhhf;
    const int* doneP = FLAGS + 1024 + g * 16;
    int* readyP = FLAGS + g * 32 + half * 16;

    // hoist this wave's 6 tiles (w, w+8, ..., w+40): weights + biases to registers
    f16x8 wA[6][4];
    float bb[6][4];
    #pragma unroll
    for (int ti = 0; ti < 6; ++ti) {
      const int tile = w + 8 * ti;
      #pragma unroll
      for (int kc = 0; kc < 4; ++kc)
        wA[ti][kc] = *(const f16x8*)(wsd + (size_t)(8 + kc) * 24576 + tile * 512);
      float4 bias = *(const float4*)(bih + tile * 16 + lq * 4);
      if (tile < 32) {                         // fold b_hh into r,z xp (n stays separate)
        float4 b2 = *(const float4*)(bhh + tile * 16 + lq * 4);
        bias.x += b2.x; bias.y += b2.y; bias.z += b2.z; bias.w += b2.w;
      }
      bb[ti][0] = bias.x; bb[ti][1] = bias.y; bb[ti][2] = bias.z; bb[ti][3] = bias.w;
    }

    for (int c = 0; c < nch; ++c) {
      if (c >= 2) { if (tid == 0) poll_ge(doneP, c - 2); __syncthreads(); }
      _Float16* slab = XP + (size_t)((c & 1) * 32 + g) * XPSLAB;
      #pragma unroll
      for (int batch = 0; batch < 2; ++batch) {
        #pragma unroll
        for (int sb = 0; sb < 4; ++sb) {       // stage x for 4 s-values
          int s = c * 16 + half * 8 + batch * 4 + sb;
          int p = dir ? (lenr - 1 - s) : s;
          p = min(max(p, 0), T_ - 1);
          int tok = seqs[(size_t)rowb * T_ + p];
          float4 f = *(const float4*)(embed + (size_t)tok * E_ + q * 4);
          f16x4 h4; h4[0] = (_Float16)f.x; h4[1] = (_Float16)f.y;
          h4[2] = (_Float16)f.z; h4[3] = (_Float16)f.w;
          *(f16x4*)(xs + ((size_t)sb * 16 + chain) * 136 + q * 4) = h4;
        }
        __syncthreads();
        f16x8 bx[4][4];
        #pragma unroll
        for (int sb = 0; sb < 4; ++sb)
          #pragma unroll
          for (int kc = 0; kc < 4; ++kc)
            bx[sb][kc] = *(const f16x8*)(xs + ((size_t)sb * 16 + lm) * 136 + kc * 32 + lq * 8);
        #pragma unroll
        for (int ti = 0; ti < 6; ++ti) {       // tiles partitioned across waves
          const int tile = w + 8 * ti;
          f32x4 acc[4] = {};
          #pragma unroll
          for (int kc = 0; kc < 4; ++kc) {
            acc[0] = __builtin_amdgcn_mfma_f32_16x16x32_f16(wA[ti][kc], bx[0][kc], acc[0], 0, 0, 0);
            acc[1] = __builtin_amdgcn_mfma_f32_16x16x32_f16(wA[ti][kc], bx[1][kc], acc[1], 0, 0, 0);
            acc[2] = __builtin_amdgcn_mfma_f32_16x16x32_f16(wA[ti][kc], bx[2][kc], acc[2], 0, 0, 0);
            acc[3] = __builtin_amdgcn_mfma_f32_16x16x32_f16(wA[ti][kc], bx[3][kc], acc[3], 0, 0, 0);
          }
          #pragma unroll
          for (int sb = 0; sb < 4; ++sb) {
            int s_local = half * 8 + batch * 4 + sb;
            f16x4 o;
            #pragma unroll
            for (int i = 0; i < 4; ++i) o[i] = (_Float16)(acc[sb][i] + bb[ti][i]);
            *(f16x4*)(slab + (size_t)s_local * 12288 + tile * 256 + lq * 64 + lm * 4) = o;
          }
        }
        __syncthreads();                       // drains; xstage reusable
      }
      if (tid == 0)
        __hip_atomic_store(readyP, c + 1, __ATOMIC_RELEASE, __HIP_MEMORY_SCOPE_AGENT);
    }
  }
}

// ---------------- final FC: out[b][c] = hcat[b] . W_fc[c] + b_fc[c] ----------------
__global__ __launch_bounds__(512) void fc_kernel(
    const float* __restrict__ hcat, const float* __restrict__ wfc,
    const float* __restrict__ bfc, float* __restrict__ out)
{
  const int b = blockIdx.x, t = threadIdx.x;
  float h  = hcat[(size_t)b * 512 + t];
  float p0 = h * wfc[t];
  float p1 = h * wfc[512 + t];
  #pragma unroll
  for (int off = 32; off > 0; off >>= 1) {
    p0 += __shfl_down(p0, off);
    p1 += __shfl_down(p1, off);
  }
  __shared__ float s0[8], s1[8];
  if ((t & 63) == 0) { s0[t >> 6] = p0; s1[t >> 6] = p1; }
  __syncthreads();
  if (t == 0) {
    float a = bfc[0], c = bfc[1];
    #pragma unroll
    for (int i = 0; i < 8; ++i) { a += s0[i]; c += s1[i]; }
    out[b * 2 + 0] = a;
    out[b * 2 + 1] = c;
  }
}

extern "C" void kernel_launch(void* const* d_in, const int* in_sizes, int n_in,
                              void* d_out, int out_size, void* d_ws, size_t ws_size,
                              hipStream_t stream)
{
  (void)in_sizes; (void)n_in; (void)out_size; (void)ws_size;
  const int*   seqs  = (const int*)d_in[0];
  const int*   lens  = (const int*)d_in[1];
  const float* embed = (const float*)d_in[2];
  const float* wihf  = (const float*)d_in[3];
  const float* whhf  = (const float*)d_in[4];
  const float* bihf  = (const float*)d_in[5];
  const float* bhhf  = (const float*)d_in[6];
  const float* wihb  = (const float*)d_in[7];
  const float* whhb  = (const float*)d_in[8];
  const float* bihb  = (const float*)d_in[9];
  const float* bhhb  = (const float*)d_in[10];
  const float* wfc   = (const float*)d_in[11];
  const float* bfc   = (const float*)d_in[12];
  float* out = (float*)d_out;

  // workspace layout (~25.6 MB)
  char* ws = (char*)d_ws;
  _Float16* WSW = (_Float16*)ws;                          // 1,179,648 B
  size_t off = 1179648;
  _Float16* XP  = (_Float16*)(ws + off); off += (size_t)2 * 32 * XPSLAB * 2;  // 25,165,824 B
  float* HCAT   = (float*)(ws + off);    off += (size_t)B_ * 2 * H_ * 4;      // 524,288 B
  int* ORDER    = (int*)(ws + off);      off += 1024;
  int* FLAGS    = (int*)(ws + off);      off += 6144;     // ready[1024] + done[512]

  prep_kernel<<<288, 256, 0, stream>>>(whhf, whhb, wihf, wihb, WSW);
  sort_kernel<<<1, 256, 0, stream>>>(lens, ORDER, FLAGS);
  fused_kernel<<<96, 512, 0, stream>>>(WSW, seqs, embed, bihf, bhhf, bihb, bhhb,
                                       lens, ORDER, XP, FLAGS, HCAT);
  fc_kernel<<<B_, 512, 0, stream>>>(HCAT, wfc, bfc, out);
}